// Round 19
// baseline (724.994 us; speedup 1.0000x reference)
//
#include <hip/hip_runtime.h>

// CausaFormer forward on MI355X. fp16 MFMA GEMMs w/ fp32 accumulate.
// B=2, L=1024, D=1024, NL=6, H=16, DK=64.
// R19: R18 base (700.4us) + emb_cvt union: embedding GEMM blocks (y<32)
//      co-dispatched with flat weight-cvt blocks (y>=32, segs outw+layer
//      weights; 2 NT loads/iter). Small cvt (x_in, emb_w) runs first.

typedef _Float16 f16;
typedef _Float16 f16x8 __attribute__((ext_vector_type(8)));
typedef _Float16 f16x4v __attribute__((ext_vector_type(4)));
typedef float f32x4 __attribute__((ext_vector_type(4)));

__device__ __forceinline__ void gload16(const void* g, void* l) {
  __builtin_amdgcn_global_load_lds((const __attribute__((address_space(1))) void*)g,
                                   (__attribute__((address_space(3))) void*)l, 16, 0, 0);
}

// Epilogue modes
enum {
  EPI_F16 = 0,   // f16 store, no bias           (cm@x)
  EPI_F16B,      // f16 store + bias             (embedding)
  EPI_SIG,       // sigmoid(v+bias) -> f16       (causal-graph gate)
  EPI_RELU,      // relu(v+bias) -> f16          (fc1)
  EPI_QKV3,      // fused q/k/v: q,k -> [B,H,L,DK]; v -> [B,H,DK,L]
  EPI_RESID,     // v+bias -> f32 C and f16 C2   (wo: residual + fc1 input)
  EPI_FC2,       // v+bias+resid -> f32          (fc2: pre-LN sum)
  EPI_OUT        // v+bias -> f32                (final projection)
};

struct GP {
  const f16* A; const f16* W; const f16* W2; const f16* W3;
  const float* bias; const float* bias2; const float* bias3;
  void* C; void* C2; void* C3; const float* resid;
  int lda; int ldw; int ldc;
  long long sA; long long sW; long long sC;
};

// NT GEMM: C[m][n] = epi( sum_k A[m][k] * W[n][k] ), K=1024 fixed (16 steps).
// 64x64 tile, BK=64, 8 waves (512 thr), wave tile 16x32. R6/R8 schedule:
// 4-buffer LDS, stage-ahead-2, counted vmcnt (4/2/0), one barrier/K-step.
template<int EPI>
__global__ __launch_bounds__(512, 4) void gemm_nt(GP p) {
  __shared__ __align__(16) f16 As[4][64 * 64];
  __shared__ __align__(16) f16 Bs[4][64 * 64];

  const int tid = threadIdx.x;
  const int lane = tid & 63;
  const int wid = tid >> 6;
  const int wr = wid >> 1;          // 0..3: 16-row group
  const int wc = wid & 1;           // 0..1: 32-col half
  const int z = blockIdx.z;
  const int m0 = blockIdx.y * 64;
  const int n0 = blockIdx.x * 64;

  const f16* Ab = p.A + (long long)z * p.sA;
  const f16* Wb;
  int n0l = n0, nm = 0;
  if constexpr (EPI == EPI_QKV3) {
    nm = n0 >> 10;
    Wb = (nm == 0 ? p.W : nm == 1 ? p.W2 : p.W3);
    n0l = n0 & 1023;
  } else {
    Wb = p.W + (long long)z * p.sW;
  }

  auto stage = [&](int buf, int t) {  // 2 gload16 per thread (1 A + 1 B)
    const int ko = t * 64;
    const int row = tid >> 3, ch = tid & 7;      // 8 x 16B chunks per 128B row
    const int sk = ((ch ^ (row & 7)) << 3);      // pre-swizzled source k-offset
    gload16(Ab + (long long)(m0 + row) * p.lda + ko + sk, &As[buf][tid * 8]);
    gload16(Wb + (long long)(n0l + row) * p.ldw + ko + sk, &Bs[buf][tid * 8]);
  };

  stage(0, 0);
  stage(1, 1);

  f32x4 acc[2] = {};
  const int lr = lane & 15;
  const int lg = lane >> 4;

  for (int t = 0; t < 16; ++t) {
    if (t + 2 < 16) stage((t + 2) & 3, t + 2);
    if (t + 2 < 16)      asm volatile("s_waitcnt vmcnt(4)" ::: "memory");
    else if (t + 1 < 16) asm volatile("s_waitcnt vmcnt(2)" ::: "memory");
    else                 asm volatile("s_waitcnt vmcnt(0)" ::: "memory");
    __builtin_amdgcn_s_barrier();
    const int cur = t & 3;
#pragma unroll
    for (int ks = 0; ks < 2; ++ks) {
      f16x8 fa, fb[2];
      {
        const int r = wr * 16 + lr;
        fa = *(const f16x8*)((const char*)&As[cur][0] + r * 128 +
                             (((ks * 4 + lg) ^ (r & 7)) << 4));
      }
#pragma unroll
      for (int j = 0; j < 2; ++j) {
        const int r = wc * 32 + j * 16 + lr;
        fb[j] = *(const f16x8*)((const char*)&Bs[cur][0] + r * 128 +
                                (((ks * 4 + lg) ^ (r & 7)) << 4));
      }
#pragma unroll
      for (int j = 0; j < 2; ++j)
        acc[j] = __builtin_amdgcn_mfma_f32_16x16x32_f16(fa, fb[j], acc[j], 0, 0, 0);
    }
    // all LDS reads of buf cur complete before any wave passes next barrier
    asm volatile("s_waitcnt lgkmcnt(0)" ::: "memory");
  }

  // ---- epilogue: D[row=(lane>>4)*4+r][col=lane&15] per frag ----
  const int rq = lg * 4;
  const float* bp = p.bias;
  if constexpr (EPI == EPI_QKV3)
    bp = nm == 0 ? p.bias : nm == 1 ? p.bias2 : p.bias3;
#pragma unroll
  for (int j = 0; j < 2; ++j) {
    const int colb = n0l + wc * 32 + j * 16 + lr;
    float bv = 0.f;
    if constexpr (EPI != EPI_F16) bv = bp ? bp[colb] : 0.f;
#pragma unroll
    for (int r = 0; r < 4; ++r) {
      const int row = m0 + wr * 16 + rq + r;
      float v = acc[j][r] + bv;
      if constexpr (EPI == EPI_SIG)  v = 1.f / (1.f + __expf(-v));
      if constexpr (EPI == EPI_RELU) v = fmaxf(v, 0.f);
      if constexpr (EPI == EPI_F16 || EPI == EPI_F16B || EPI == EPI_SIG || EPI == EPI_RELU) {
        ((f16*)p.C)[(long long)z * p.sC + (long long)row * p.ldc + colb] = (f16)v;
      } else if constexpr (EPI == EPI_QKV3) {
        const int b = row >> 10, l = row & 1023;
        const int h = colb >> 6, dk = colb & 63;
        if (nm == 2)
          ((f16*)p.C3)[((((long long)b * 16 + h) * 64 + dk) << 10) + l] = (f16)v;
        else
          ((f16*)(nm == 0 ? p.C : p.C2))[((((long long)b * 16 + h) * 1024 + l) << 6) + dk] = (f16)v;
      } else if constexpr (EPI == EPI_RESID) {
        const long long idx = (long long)row * 1024 + colb;
        ((float*)p.C)[idx] = v;
        ((f16*)p.C2)[idx] = (f16)v;
      } else if constexpr (EPI == EPI_FC2) {
        const long long idx = (long long)row * 1024 + colb;
        ((float*)p.C)[idx] = v + p.resid[idx];
      } else if constexpr (EPI == EPI_OUT) {
        ((float*)p.C)[(long long)row * 1024 + colb] = v;
      }
    }
  }
}

// Union kernel: blocks y<32 run the SIG GEMM; blocks y>=32 transpose xh.
__global__ __launch_bounds__(512, 4) void sig_tr(GP p) {
  __shared__ __align__(16) f16 smem[32768];   // 64KB

  const int tid = threadIdx.x;

  if (blockIdx.y >= 32) {
    constexpr int RP = 68;
    f16* T = smem;
    const int idx = (blockIdx.y - 32) * 16 + blockIdx.x;
    const int z = idx >> 8;
    const int rem = idx & 255;
    const int l0 = (rem >> 4) * 64;
    const int c0 = (rem & 15) * 64;
    const long long zb = (long long)z * (1024 * 1024);
    const f16* x = p.W2;
    f16* xt = (f16*)p.C2;
    {
      const int r = tid >> 3, c8 = tid & 7;
      f16x8 v = *(const f16x8*)(x + zb + (long long)(l0 + r) * 1024 + c0 + c8 * 8);
#pragma unroll
      for (int j = 0; j < 8; ++j)
        T[(c8 * 8 + j) * RP + r] = v[j];
    }
    __syncthreads();
    {
      const int c = tid >> 3, r8 = tid & 7;
      f16x4v a = *(const f16x4v*)(&T[c * RP + r8 * 8]);
      f16x4v bb = *(const f16x4v*)(&T[c * RP + r8 * 8 + 4]);
      f16x8 w = {a[0], a[1], a[2], a[3], bb[0], bb[1], bb[2], bb[3]};
      *(f16x8*)(xt + zb + (long long)(c0 + c) * 1024 + l0 + r8 * 8) = w;
    }
    return;
  }

  // ---- SIG GEMM (identical schedule to gemm_nt<EPI_SIG>, z=0) ----
  f16* As = smem;                 // [4][64*64]
  f16* Bs = smem + 16384;         // [4][64*64]
  const int lane = tid & 63;
  const int wid = tid >> 6;
  const int wr = wid >> 1;
  const int wc = wid & 1;
  const int m0 = blockIdx.y * 64;
  const int n0 = blockIdx.x * 64;
  const f16* Ab = p.A;
  const f16* Wb = p.W;

  auto stage = [&](int buf, int t) {
    const int ko = t * 64;
    const int row = tid >> 3, ch = tid & 7;
    const int sk = ((ch ^ (row & 7)) << 3);
    gload16(Ab + (long long)(m0 + row) * p.lda + ko + sk, As + buf * 4096 + tid * 8);
    gload16(Wb + (long long)(n0 + row) * p.ldw + ko + sk, Bs + buf * 4096 + tid * 8);
  };

  stage(0, 0);
  stage(1, 1);

  f32x4 acc[2] = {};
  const int lr = lane & 15;
  const int lg = lane >> 4;

  for (int t = 0; t < 16; ++t) {
    if (t + 2 < 16) stage((t + 2) & 3, t + 2);
    if (t + 2 < 16)      asm volatile("s_waitcnt vmcnt(4)" ::: "memory");
    else if (t + 1 < 16) asm volatile("s_waitcnt vmcnt(2)" ::: "memory");
    else                 asm volatile("s_waitcnt vmcnt(0)" ::: "memory");
    __builtin_amdgcn_s_barrier();
    const int cur = t & 3;
#pragma unroll
    for (int ks = 0; ks < 2; ++ks) {
      f16x8 fa, fb[2];
      {
        const int r = wr * 16 + lr;
        fa = *(const f16x8*)((const char*)(As + cur * 4096) + r * 128 +
                             (((ks * 4 + lg) ^ (r & 7)) << 4));
      }
#pragma unroll
      for (int j = 0; j < 2; ++j) {
        const int r = wc * 32 + j * 16 + lr;
        fb[j] = *(const f16x8*)((const char*)(Bs + cur * 4096) + r * 128 +
                                (((ks * 4 + lg) ^ (r & 7)) << 4));
      }
#pragma unroll
      for (int j = 0; j < 2; ++j)
        acc[j] = __builtin_amdgcn_mfma_f32_16x16x32_f16(fa, fb[j], acc[j], 0, 0, 0);
    }
    asm volatile("s_waitcnt lgkmcnt(0)" ::: "memory");
  }

  const int rq = lg * 4;
#pragma unroll
  for (int j = 0; j < 2; ++j) {
    const int colb = n0 + wc * 32 + j * 16 + lr;
    const float bv = p.bias[colb];
#pragma unroll
    for (int r = 0; r < 4; ++r) {
      const int row = m0 + wr * 16 + rq + r;
      float v = acc[j][r] + bv;
      v = 1.f / (1.f + __expf(-v));
      ((f16*)p.C)[(long long)row * p.ldc + colb] = (f16)v;
    }
  }
}

// Union kernel: blocks y<32 run the embedding GEMM (xh = xh0 @ emb_w^T + b);
// blocks y>=32 convert the remaining fp32 weights (flat quad space, 8 segs,
// 2 independent NT loads/iter for in-flight depth under the LDS-capped
// occupancy). Embedding depends only on segs 0-1 (converted beforehand).
struct ECArgs {
  const f16* A; const f16* W; const float* bias; f16* C;
  const float* src[8]; f16* dst[8]; int cum[9];   // cumulative float4 counts
};
__global__ __launch_bounds__(512, 4) void emb_cvt(ECArgs a) {
  __shared__ __align__(16) f16 smem[32768];   // 64KB
  const int tid = threadIdx.x;

  if (blockIdx.y >= 32) {
    const int cb = (blockIdx.y - 32) * 16 + blockIdx.x;   // 0..511
    const int T = 512 * 512;
    const int total = a.cum[8];
    for (int q = cb * 512 + tid; q < total; q += 2 * T) {
      int seg = 0;
#pragma unroll
      for (int s = 1; s < 8; ++s) seg += (q >= a.cum[s]) ? 1 : 0;
      const int off = q - a.cum[seg];
      const int q2 = q + T;
      int seg2 = 0, off2 = 0;
      const bool has2 = q2 < total;
      if (has2) {
#pragma unroll
        for (int s = 1; s < 8; ++s) seg2 += (q2 >= a.cum[s]) ? 1 : 0;
        off2 = q2 - a.cum[seg2];
      }
      // issue both loads before converting (independent, both in flight)
      f32x4 v1 = __builtin_nontemporal_load((const f32x4*)a.src[seg] + off);
      f32x4 v2 = {};
      if (has2) v2 = __builtin_nontemporal_load((const f32x4*)a.src[seg2] + off2);
      f16x4v o1 = {(f16)v1[0], (f16)v1[1], (f16)v1[2], (f16)v1[3]};
      ((f16x4v*)a.dst[seg])[off] = o1;
      if (has2) {
        f16x4v o2 = {(f16)v2[0], (f16)v2[1], (f16)v2[2], (f16)v2[3]};
        ((f16x4v*)a.dst[seg2])[off2] = o2;
      }
    }
    return;
  }

  // ---- embedding GEMM (identical schedule to gemm_nt<EPI_F16B>, z=0) ----
  f16* As = smem;
  f16* Bs = smem + 16384;
  const int lane = tid & 63;
  const int wid = tid >> 6;
  const int wr = wid >> 1;
  const int wc = wid & 1;
  const int m0 = blockIdx.y * 64;
  const int n0 = blockIdx.x * 64;
  const f16* Ab = a.A;
  const f16* Wb = a.W;

  auto stage = [&](int buf, int t) {
    const int ko = t * 64;
    const int row = tid >> 3, ch = tid & 7;
    const int sk = ((ch ^ (row & 7)) << 3);
    gload16(Ab + (long long)(m0 + row) * 1024 + ko + sk, As + buf * 4096 + tid * 8);
    gload16(Wb + (long long)(n0 + row) * 1024 + ko + sk, Bs + buf * 4096 + tid * 8);
  };

  stage(0, 0);
  stage(1, 1);

  f32x4 acc[2] = {};
  const int lr = lane & 15;
  const int lg = lane >> 4;

  for (int t = 0; t < 16; ++t) {
    if (t + 2 < 16) stage((t + 2) & 3, t + 2);
    if (t + 2 < 16)      asm volatile("s_waitcnt vmcnt(4)" ::: "memory");
    else if (t + 1 < 16) asm volatile("s_waitcnt vmcnt(2)" ::: "memory");
    else                 asm volatile("s_waitcnt vmcnt(0)" ::: "memory");
    __builtin_amdgcn_s_barrier();
    const int cur = t & 3;
#pragma unroll
    for (int ks = 0; ks < 2; ++ks) {
      f16x8 fa, fb[2];
      {
        const int r = wr * 16 + lr;
        fa = *(const f16x8*)((const char*)(As + cur * 4096) + r * 128 +
                             (((ks * 4 + lg) ^ (r & 7)) << 4));
      }
#pragma unroll
      for (int j = 0; j < 2; ++j) {
        const int r = wc * 32 + j * 16 + lr;
        fb[j] = *(const f16x8*)((const char*)(Bs + cur * 4096) + r * 128 +
                                (((ks * 4 + lg) ^ (r & 7)) << 4));
      }
#pragma unroll
      for (int j = 0; j < 2; ++j)
        acc[j] = __builtin_amdgcn_mfma_f32_16x16x32_f16(fa, fb[j], acc[j], 0, 0, 0);
    }
    asm volatile("s_waitcnt lgkmcnt(0)" ::: "memory");
  }

  const int rq = lg * 4;
#pragma unroll
  for (int j = 0; j < 2; ++j) {
    const int colb = n0 + wc * 32 + j * 16 + lr;
    const float bv = a.bias[colb];
#pragma unroll
    for (int r = 0; r < 4; ++r) {
      const int row = m0 + wr * 16 + rq + r;
      a.C[(long long)row * 1024 + colb] = (f16)(acc[j][r] + bv);
    }
  }
}

// Fused flash attention, transposed-softmax form (R17: T5 setprio).
__global__ __launch_bounds__(256, 4) void fattn(const f16* __restrict__ q,
                                                const f16* __restrict__ kk,
                                                const f16* __restrict__ vt,
                                                f16* __restrict__ out) {
  __shared__ __align__(16) f16 Ks[2][64 * 64];   // [j][dk] rows 128B, swizzled
  __shared__ __align__(16) f16 Vs[2][64 * 64];   // [dk][j] rows 128B, swizzled
  __shared__ __align__(16) f16 Ps[4][16 * 64];   // Q staging, then per-wave P^T

  const int tid = threadIdx.x;
  const int lane = tid & 63;
  const int wid = tid >> 6;
  const int lr = lane & 15;
  const int lg = lane >> 4;
  const int bh = blockIdx.y;
  const int b = bh >> 4, h = bh & 15;
  const int q0 = blockIdx.x * 64;

  const f16* qp = q + (long long)bh * 65536;
  const f16* kp = kk + (long long)bh * 65536;
  const f16* vp = vt + (long long)bh * 65536;
  char* pbase = (char*)&Ps[0][0];

#pragma unroll
  for (int u = 0; u < 2; ++u) {
    const int c = u * 4 + wid;
    const int s = c * 64 + lane;
    const int row = s >> 3, ch = s & 7;
    gload16(qp + (long long)(q0 + row) * 64 + ((ch ^ (row & 7)) << 3),
            pbase + c * 1024);
  }
  asm volatile("s_waitcnt vmcnt(0)" ::: "memory");
  __syncthreads();
  f16x8 qf[2];
#pragma unroll
  for (int ks = 0; ks < 2; ++ks) {
    const int row = wid * 16 + lr;
    qf[ks] = *(const f16x8*)(pbase + row * 128 + (((ks * 4 + lg) ^ (lr & 7)) << 4));
  }
  asm volatile("s_waitcnt lgkmcnt(0)" ::: "memory");
  __syncthreads();

  f32x4 o[4] = {};
  f32x4 ol = {};
  float m_r = -1e30f;

  const f16x8 ones = {(f16)1.f, (f16)1.f, (f16)1.f, (f16)1.f,
                      (f16)1.f, (f16)1.f, (f16)1.f, (f16)1.f};

  auto stage = [&](int buf, int t) {
    const int j0 = t * 64;
#pragma unroll
    for (int u = 0; u < 2; ++u) {
      const int c = u * 4 + wid;
      const int s = c * 64 + lane;
      const int row = s >> 3, ch = s & 7;
      const int sch = (ch ^ (row & 7)) * 8;
      gload16(kp + (long long)(j0 + row) * 64 + sch, &Ks[buf][c * 512]);
      gload16(vp + (long long)row * 1024 + j0 + sch, &Vs[buf][c * 512]);
    }
  };

  stage(0, 0);

  constexpr float SCL = 0.125f * 1.44269504089f;
  for (int t = 0; t < 16; ++t) {
    asm volatile("s_waitcnt vmcnt(0)" ::: "memory");
    __builtin_amdgcn_s_barrier();
    if (t + 1 < 16) stage((t + 1) & 1, t + 1);
    const int cur = t & 1;

    f32x4 s[4] = {};
    __builtin_amdgcn_s_setprio(1);
#pragma unroll
    for (int ks = 0; ks < 2; ++ks) {
      f16x8 fk[4];
#pragma unroll
      for (int jf = 0; jf < 4; ++jf) {
        const int j = jf * 16 + lr;
        fk[jf] = *(const f16x8*)((const char*)&Ks[cur][0] + j * 128 +
                                 (((ks * 4 + lg) ^ (j & 7)) << 4));
      }
#pragma unroll
      for (int jf = 0; jf < 4; ++jf)
        s[jf] = __builtin_amdgcn_mfma_f32_16x16x32_f16(fk[jf], qf[ks], s[jf], 0, 0, 0);
    }
    __builtin_amdgcn_s_setprio(0);

    float pm = s[0][0];
#pragma unroll
    for (int jf = 0; jf < 4; ++jf)
#pragma unroll
      for (int r = 0; r < 4; ++r) pm = fmaxf(pm, s[jf][r]);
    pm = fmaxf(pm, __shfl_xor(pm, 16));
    pm = fmaxf(pm, __shfl_xor(pm, 32));
    if (__any(pm > m_r)) {
      const float mn = fmaxf(m_r, pm);
      const float sf = __builtin_exp2f((m_r - mn) * SCL);
      m_r = mn;
#pragma unroll
      for (int df = 0; df < 4; ++df)
#pragma unroll
        for (int r = 0; r < 4; ++r) o[df][r] *= sf;
#pragma unroll
      for (int r = 0; r < 4; ++r) ol[r] *= sf;
    }
    const float msc = m_r * SCL;
    float pv[4][4];
#pragma unroll
    for (int jf = 0; jf < 4; ++jf)
#pragma unroll
      for (int r = 0; r < 4; ++r)
        pv[jf][r] = __builtin_exp2f(__builtin_fmaf(s[jf][r], SCL, -msc));
    if (t == 0 && lg == 0) pv[0][0] *= 0.5f;

#pragma unroll
    for (int jf = 0; jf < 4; ++jf) {
      f16x4v pk = {(f16)pv[jf][0], (f16)pv[jf][1], (f16)pv[jf][2], (f16)pv[jf][3]};
      const int j0 = jf * 16 + lg * 4;
      *(f16x4v*)(pbase + wid * 2048 + lr * 128 +
                 (((j0 >> 3) ^ (lr & 7)) << 4) + (j0 & 7) * 2) = pk;
    }
    asm volatile("s_waitcnt lgkmcnt(0)" ::: "memory");
    __builtin_amdgcn_sched_barrier(0);

    __builtin_amdgcn_s_setprio(1);
#pragma unroll
    for (int ks = 0; ks < 2; ++ks) {
      f16x8 fp, fv[4];
      fp = *(const f16x8*)(pbase + wid * 2048 + lr * 128 +
                           (((ks * 4 + lg) ^ (lr & 7)) << 4));
#pragma unroll
      for (int df = 0; df < 4; ++df) {
        const int d = df * 16 + lr;
        fv[df] = *(const f16x8*)((const char*)&Vs[cur][0] + d * 128 +
                                 (((ks * 4 + lg) ^ (d & 7)) << 4));
      }
#pragma unroll
      for (int df = 0; df < 4; ++df)
        o[df] = __builtin_amdgcn_mfma_f32_16x16x32_f16(fv[df], fp, o[df], 0, 0, 0);
      ol = __builtin_amdgcn_mfma_f32_16x16x32_f16(ones, fp, ol, 0, 0, 0);
    }
    __builtin_amdgcn_s_setprio(0);
    if (t == 0) {
      const float hv = __shfl(pv[0][0], lane & 15);
#pragma unroll
      for (int r = 0; r < 4; ++r) ol[r] += hv;
    }
    asm volatile("s_waitcnt lgkmcnt(0)" ::: "memory");
  }

  const float inv = 1.f / ol[0];
  const long long rowi = q0 + wid * 16 + lr;
#pragma unroll
  for (int df = 0; df < 4; ++df) {
    f16x4v ov = {(f16)(o[df][0] * inv), (f16)(o[df][1] * inv),
                 (f16)(o[df][2] * inv), (f16)(o[df][3] * inv)};
    *(f16x4v*)(out + (long long)b * 1048576 + rowi * 1024 + h * 64 +
               df * 16 + lg * 4) = ov;
  }
}

// LayerNorm over D=1024, fp32 in, f16 out.
__global__ __launch_bounds__(256) void ln_k(const float* __restrict__ pre,
                                            const float* __restrict__ w,
                                            const float* __restrict__ b,
                                            f16* __restrict__ out) {
  const long long row = blockIdx.x;
  const int t = threadIdx.x;
  const float* x = pre + row * 1024;
  float4 v = *(const float4*)(x + t * 4);
  float s = v.x + v.y + v.z + v.w;
  float s2 = v.x * v.x + v.y * v.y + v.z * v.z + v.w * v.w;
#pragma unroll
  for (int o = 1; o < 64; o <<= 1) { s += __shfl_xor(s, o); s2 += __shfl_xor(s2, o); }
  __shared__ float rs[4], rs2[4];
  if ((t & 63) == 0) { rs[t >> 6] = s; rs2[t >> 6] = s2; }
  __syncthreads();
  s = rs[0] + rs[1] + rs[2] + rs[3];
  s2 = rs2[0] + rs2[1] + rs2[2] + rs2[3];
  const float mean = s * (1.f / 1024.f);
  const float var = s2 * (1.f / 1024.f) - mean * mean;
  const float inv = rsqrtf(var + 1e-5f);
  f16x4v o4;
#pragma unroll
  for (int c = 0; c < 4; ++c) {
    const float xv = (&v.x)[c];
    o4[c] = (f16)((xv - mean) * inv * w[t * 4 + c] + b[t * 4 + c]);
  }
  *(f16x4v*)(out + row * 1024 + t * 4) = o4;
}

// fp32 -> fp16, segments parallel across blockIdx.y (small prologue cvt).
struct CvtArgs {
  const float* src[10];
  f16* dst[10];
  int n4[10];
};
__global__ __launch_bounds__(256) void cvt_par(CvtArgs a) {
  const int seg = blockIdx.y;
  const f32x4* in = (const f32x4*)a.src[seg];
  f16x4v* out = (f16x4v*)a.dst[seg];
  const int n = a.n4[seg];
  const int stride = gridDim.x * 256;
  for (int i = blockIdx.x * 256 + threadIdx.x; i < n; i += stride) {
    f32x4 v = __builtin_nontemporal_load(&in[i]);
    f16x4v o = {(f16)v[0], (f16)v[1], (f16)v[2], (f16)v[3]};
    out[i] = o;
  }
}

extern "C" void kernel_launch(void* const* d_in, const int* in_sizes, int n_in,
                              void* d_out, int out_size, void* d_ws, size_t ws_size,
                              hipStream_t stream) {
  (void)in_sizes; (void)n_in; (void)out_size; (void)ws_size;
  const float* x_in  = (const float*)d_in[0];
  const float* emb_w = (const float*)d_in[1];
  const float* emb_b = (const float*)d_in[2];
  const float* cg_w  = (const float*)d_in[3];
  const float* cg_b  = (const float*)d_in[4];
  const float* wq    = (const float*)d_in[5];
  const float* bq    = (const float*)d_in[6];
  const float* wk    = (const float*)d_in[7];
  const float* bk    = (const float*)d_in[8];
  const float* wv    = (const float*)d_in[9];
  const float* bv    = (const float*)d_in[10];
  const float* wo    = (const float*)d_in[11];
  const float* bo    = (const float*)d_in[12];
  const float* fc1w  = (const float*)d_in[13];
  const float* fc1b  = (const float*)d_in[14];
  const float* fc2w  = (const float*)d_in[15];
  const float* fc2b  = (const float*)d_in[16];
  const float* lnw   = (const float*)d_in[17];
  const float* lnb   = (const float*)d_in[18];
  const float* outw  = (const float*)d_in[19];
  const float* outb  = (const float*)d_in[20];
  float* outp = (float*)d_out;

  const size_t M1 = 1024ull * 1024ull;
  char* wsp = (char*)d_ws;
  size_t off = 0;
  auto alloc = [&](size_t bytes) -> void* {
    void* r = wsp + off;
    off += (bytes + 255) & ~(size_t)255;
    return r;
  };

  // fp16 weights
  f16* embw_h = (f16*)alloc(M1 * 2);
  f16* outw_h = (f16*)alloc(M1 * 2);
  f16* cgw_h  = (f16*)alloc(6 * M1 * 2);
  f16* wq_h   = (f16*)alloc(6 * M1 * 2);
  f16* wk_h   = (f16*)alloc(6 * M1 * 2);
  f16* wv_h   = (f16*)alloc(6 * M1 * 2);
  f16* wo_h   = (f16*)alloc(6 * M1 * 2);
  f16* fc1_h  = (f16*)alloc(6 * M1 * 2);
  f16* fc2_h  = (f16*)alloc(6 * M1 * 2);
  // fp16 activations
  f16* xh0   = (f16*)alloc(2 * M1 * 2);
  f16* xh    = (f16*)alloc(2 * M1 * 2);
  f16* xT    = (f16*)alloc(2 * M1 * 2);
  f16* cmb   = (f16*)alloc(2 * M1 * 2);
  f16* x2    = (f16*)alloc(2 * M1 * 2);
  f16* qb    = (f16*)alloc(2 * M1 * 2);
  f16* kbuf  = (f16*)alloc(2 * M1 * 2);
  f16* vT    = (f16*)alloc(2 * M1 * 2);
  f16* attnb = (f16*)alloc(2 * M1 * 2);
  f16* xf    = (f16*)alloc(2 * M1 * 2);
  f16* h1    = (f16*)alloc(2 * M1 * 2);
  // fp32 buffers
  float* resid = (float*)alloc(2 * M1 * 4);
  float* pre   = (float*)alloc(2 * M1 * 4);

  // ---- prologue cvt: only what the embedding GEMM needs (x_in, emb_w) ----
  CvtArgs ca;
  ca.src[0] = x_in;  ca.dst[0] = xh0;    ca.n4[0] = (int)(2 * M1 / 4);
  ca.src[1] = emb_w; ca.dst[1] = embw_h; ca.n4[1] = (int)(M1 / 4);
  cvt_par<<<dim3(512, 2), 256, 0, stream>>>(ca);

  // ---- union: embedding GEMM + remaining weight conversions ----
  ECArgs ea;
  ea.A = xh0; ea.W = embw_h; ea.bias = emb_b; ea.C = xh;
  const float* srcs[8] = {outw, cg_w, wq, wk, wv, wo, fc1w, fc2w};
  f16* dsts[8] = {outw_h, cgw_h, wq_h, wk_h, wv_h, wo_h, fc1_h, fc2_h};
  const int q1 = (int)(M1 / 4), q6 = (int)(6 * M1 / 4);
  int quads[8] = {q1, q6, q6, q6, q6, q6, q6, q6};
  ea.cum[0] = 0;
  for (int i = 0; i < 8; ++i) {
    ea.src[i] = srcs[i]; ea.dst[i] = dsts[i];
    ea.cum[i + 1] = ea.cum[i] + quads[i];
  }
  emb_cvt<<<dim3(16, 64, 1), 512, 0, stream>>>(ea);

  for (int i = 0; i < 6; ++i) {
    const f16* cgwi = cgw_h + (size_t)i * M1;
    const f16* wqi = wq_h + (size_t)i * M1;
    const f16* wki = wk_h + (size_t)i * M1;
    const f16* wvi = wv_h + (size_t)i * M1;
    const f16* woi = wo_h + (size_t)i * M1;
    const f16* f1i = fc1_h + (size_t)i * M1;
    const f16* f2i = fc2_h + (size_t)i * M1;

    // fused: cm = sigmoid(xh @ cg_w^T + cg_b)  AND  xT = transpose(xh)
    sig_tr<<<dim3(16, 64, 1), 512, 0, stream>>>(
        GP{xh, cgwi, xh, nullptr, cg_b + i * 1024, nullptr, nullptr,
           cmb, xT, nullptr, nullptr, 1024, 1024, 1024, 0, 0, 0});

    // x2[b] = cm[b] @ x[b]  (NT against xT)
    gemm_nt<EPI_F16><<<dim3(16, 16, 2), 512, 0, stream>>>(
        GP{cmb, xT, nullptr, nullptr, nullptr, nullptr, nullptr,
           x2, nullptr, nullptr, nullptr, 1024, 1024, 1024,
           (long long)M1, (long long)M1, (long long)M1});

    // fused q/k/v projection: q,k -> [B,H,L,DK]; v -> [B,H,DK,L]
    gemm_nt<EPI_QKV3><<<dim3(48, 32, 1), 512, 0, stream>>>(
        GP{x2, wqi, wki, wvi, bq + i * 1024, bk + i * 1024, bv + i * 1024,
           qb, kbuf, vT, nullptr, 1024, 1024, 0, 0, 0, 0});

    // fused attention
    fattn<<<dim3(16, 32), 256, 0, stream>>>(qb, kbuf, vT, attnb);

    // x = attn @ wo^T + bo  -> resid (fp32) + xf (fp16)
    gemm_nt<EPI_RESID><<<dim3(16, 32, 1), 512, 0, stream>>>(
        GP{attnb, woi, nullptr, nullptr, bo + i * 1024, nullptr, nullptr,
           resid, xf, nullptr, nullptr, 1024, 1024, 0, 0, 0, 0});
    gemm_nt<EPI_RELU><<<dim3(16, 32, 1), 512, 0, stream>>>(
        GP{xf, f1i, nullptr, nullptr, fc1b + i * 1024, nullptr, nullptr,
           h1, nullptr, nullptr, nullptr, 1024, 1024, 1024, 0, 0, 0});
    gemm_nt<EPI_FC2><<<dim3(16, 32, 1), 512, 0, stream>>>(
        GP{h1, f2i, nullptr, nullptr, fc2b + i * 1024, nullptr, nullptr,
           pre, nullptr, nullptr, resid, 1024, 1024, 0, 0, 0, 0});
    ln_k<<<dim3(2048), 256, 0, stream>>>(pre, lnw + i * 1024, lnb + i * 1024, xh);
  }

  gemm_nt<EPI_OUT><<<dim3(16, 32, 1), 512, 0, stream>>>(
      GP{xh, outw_h, nullptr, nullptr, outb, nullptr, nullptr,
         outp, nullptr, nullptr, nullptr, 1024, 1024, 0, 0, 0, 0});
}

// Round 20
// 699.680 us; speedup vs baseline: 1.0362x; 1.0362x over previous
//
#include <hip/hip_runtime.h>

// CausaFormer forward on MI355X. fp16 MFMA GEMMs w/ fp32 accumulate.
// B=2, L=1024, D=1024, NL=6, H=16, DK=64.
// R20: exact revert to R18 (verified best, 700.4us). R19's emb_cvt union
//      regressed (64KB LDS capped cvt blocks at 2 blocks/CU -> 78us).
//      Final config: cvt_par(NT) -> emb GEMM -> per layer [sig_tr union,
//      x2, QKV3, fattn(T5), RESID, RELU, FC2, ln] -> out GEMM.

typedef _Float16 f16;
typedef _Float16 f16x8 __attribute__((ext_vector_type(8)));
typedef _Float16 f16x4v __attribute__((ext_vector_type(4)));
typedef float f32x4 __attribute__((ext_vector_type(4)));

__device__ __forceinline__ void gload16(const void* g, void* l) {
  __builtin_amdgcn_global_load_lds((const __attribute__((address_space(1))) void*)g,
                                   (__attribute__((address_space(3))) void*)l, 16, 0, 0);
}

// Epilogue modes
enum {
  EPI_F16 = 0,   // f16 store, no bias           (cm@x)
  EPI_F16B,      // f16 store + bias             (embedding)
  EPI_SIG,       // sigmoid(v+bias) -> f16       (causal-graph gate)
  EPI_RELU,      // relu(v+bias) -> f16          (fc1)
  EPI_QKV3,      // fused q/k/v: q,k -> [B,H,L,DK]; v -> [B,H,DK,L]
  EPI_RESID,     // v+bias -> f32 C and f16 C2   (wo: residual + fc1 input)
  EPI_FC2,       // v+bias+resid -> f32          (fc2: pre-LN sum)
  EPI_OUT        // v+bias -> f32                (final projection)
};

struct GP {
  const f16* A; const f16* W; const f16* W2; const f16* W3;
  const float* bias; const float* bias2; const float* bias3;
  void* C; void* C2; void* C3; const float* resid;
  int lda; int ldw; int ldc;
  long long sA; long long sW; long long sC;
};

// NT GEMM: C[m][n] = epi( sum_k A[m][k] * W[n][k] ), K=1024 fixed (16 steps).
// 64x64 tile, BK=64, 8 waves (512 thr), wave tile 16x32. R6/R8 schedule:
// 4-buffer LDS, stage-ahead-2, counted vmcnt (4/2/0), one barrier/K-step.
template<int EPI>
__global__ __launch_bounds__(512, 4) void gemm_nt(GP p) {
  __shared__ __align__(16) f16 As[4][64 * 64];
  __shared__ __align__(16) f16 Bs[4][64 * 64];

  const int tid = threadIdx.x;
  const int lane = tid & 63;
  const int wid = tid >> 6;
  const int wr = wid >> 1;          // 0..3: 16-row group
  const int wc = wid & 1;           // 0..1: 32-col half
  const int z = blockIdx.z;
  const int m0 = blockIdx.y * 64;
  const int n0 = blockIdx.x * 64;

  const f16* Ab = p.A + (long long)z * p.sA;
  const f16* Wb;
  int n0l = n0, nm = 0;
  if constexpr (EPI == EPI_QKV3) {
    nm = n0 >> 10;
    Wb = (nm == 0 ? p.W : nm == 1 ? p.W2 : p.W3);
    n0l = n0 & 1023;
  } else {
    Wb = p.W + (long long)z * p.sW;
  }

  auto stage = [&](int buf, int t) {  // 2 gload16 per thread (1 A + 1 B)
    const int ko = t * 64;
    const int row = tid >> 3, ch = tid & 7;      // 8 x 16B chunks per 128B row
    const int sk = ((ch ^ (row & 7)) << 3);      // pre-swizzled source k-offset
    gload16(Ab + (long long)(m0 + row) * p.lda + ko + sk, &As[buf][tid * 8]);
    gload16(Wb + (long long)(n0l + row) * p.ldw + ko + sk, &Bs[buf][tid * 8]);
  };

  stage(0, 0);
  stage(1, 1);

  f32x4 acc[2] = {};
  const int lr = lane & 15;
  const int lg = lane >> 4;

  for (int t = 0; t < 16; ++t) {
    if (t + 2 < 16) stage((t + 2) & 3, t + 2);
    if (t + 2 < 16)      asm volatile("s_waitcnt vmcnt(4)" ::: "memory");
    else if (t + 1 < 16) asm volatile("s_waitcnt vmcnt(2)" ::: "memory");
    else                 asm volatile("s_waitcnt vmcnt(0)" ::: "memory");
    __builtin_amdgcn_s_barrier();
    const int cur = t & 3;
#pragma unroll
    for (int ks = 0; ks < 2; ++ks) {
      f16x8 fa, fb[2];
      {
        const int r = wr * 16 + lr;
        fa = *(const f16x8*)((const char*)&As[cur][0] + r * 128 +
                             (((ks * 4 + lg) ^ (r & 7)) << 4));
      }
#pragma unroll
      for (int j = 0; j < 2; ++j) {
        const int r = wc * 32 + j * 16 + lr;
        fb[j] = *(const f16x8*)((const char*)&Bs[cur][0] + r * 128 +
                                (((ks * 4 + lg) ^ (r & 7)) << 4));
      }
#pragma unroll
      for (int j = 0; j < 2; ++j)
        acc[j] = __builtin_amdgcn_mfma_f32_16x16x32_f16(fa, fb[j], acc[j], 0, 0, 0);
    }
    // all LDS reads of buf cur complete before any wave passes next barrier
    asm volatile("s_waitcnt lgkmcnt(0)" ::: "memory");
  }

  // ---- epilogue: D[row=(lane>>4)*4+r][col=lane&15] per frag ----
  const int rq = lg * 4;
  const float* bp = p.bias;
  if constexpr (EPI == EPI_QKV3)
    bp = nm == 0 ? p.bias : nm == 1 ? p.bias2 : p.bias3;
#pragma unroll
  for (int j = 0; j < 2; ++j) {
    const int colb = n0l + wc * 32 + j * 16 + lr;
    float bv = 0.f;
    if constexpr (EPI != EPI_F16) bv = bp ? bp[colb] : 0.f;
#pragma unroll
    for (int r = 0; r < 4; ++r) {
      const int row = m0 + wr * 16 + rq + r;
      float v = acc[j][r] + bv;
      if constexpr (EPI == EPI_SIG)  v = 1.f / (1.f + __expf(-v));
      if constexpr (EPI == EPI_RELU) v = fmaxf(v, 0.f);
      if constexpr (EPI == EPI_F16 || EPI == EPI_F16B || EPI == EPI_SIG || EPI == EPI_RELU) {
        ((f16*)p.C)[(long long)z * p.sC + (long long)row * p.ldc + colb] = (f16)v;
      } else if constexpr (EPI == EPI_QKV3) {
        const int b = row >> 10, l = row & 1023;
        const int h = colb >> 6, dk = colb & 63;
        if (nm == 2)
          ((f16*)p.C3)[((((long long)b * 16 + h) * 64 + dk) << 10) + l] = (f16)v;
        else
          ((f16*)(nm == 0 ? p.C : p.C2))[((((long long)b * 16 + h) * 1024 + l) << 6) + dk] = (f16)v;
      } else if constexpr (EPI == EPI_RESID) {
        const long long idx = (long long)row * 1024 + colb;
        ((float*)p.C)[idx] = v;
        ((f16*)p.C2)[idx] = (f16)v;
      } else if constexpr (EPI == EPI_FC2) {
        const long long idx = (long long)row * 1024 + colb;
        ((float*)p.C)[idx] = v + p.resid[idx];
      } else if constexpr (EPI == EPI_OUT) {
        ((float*)p.C)[(long long)row * 1024 + colb] = v;
      }
    }
  }
}

// Union kernel: blocks y<32 run the SIG GEMM; blocks y>=32 transpose xh.
__global__ __launch_bounds__(512, 4) void sig_tr(GP p) {
  __shared__ __align__(16) f16 smem[32768];   // 64KB

  const int tid = threadIdx.x;

  if (blockIdx.y >= 32) {
    constexpr int RP = 68;
    f16* T = smem;
    const int idx = (blockIdx.y - 32) * 16 + blockIdx.x;
    const int z = idx >> 8;
    const int rem = idx & 255;
    const int l0 = (rem >> 4) * 64;
    const int c0 = (rem & 15) * 64;
    const long long zb = (long long)z * (1024 * 1024);
    const f16* x = p.W2;
    f16* xt = (f16*)p.C2;
    {
      const int r = tid >> 3, c8 = tid & 7;
      f16x8 v = *(const f16x8*)(x + zb + (long long)(l0 + r) * 1024 + c0 + c8 * 8);
#pragma unroll
      for (int j = 0; j < 8; ++j)
        T[(c8 * 8 + j) * RP + r] = v[j];
    }
    __syncthreads();
    {
      const int c = tid >> 3, r8 = tid & 7;
      f16x4v a = *(const f16x4v*)(&T[c * RP + r8 * 8]);
      f16x4v bb = *(const f16x4v*)(&T[c * RP + r8 * 8 + 4]);
      f16x8 w = {a[0], a[1], a[2], a[3], bb[0], bb[1], bb[2], bb[3]};
      *(f16x8*)(xt + zb + (long long)(c0 + c) * 1024 + l0 + r8 * 8) = w;
    }
    return;
  }

  // ---- SIG GEMM (identical schedule to gemm_nt<EPI_SIG>, z=0) ----
  f16* As = smem;                 // [4][64*64]
  f16* Bs = smem + 16384;         // [4][64*64]
  const int lane = tid & 63;
  const int wid = tid >> 6;
  const int wr = wid >> 1;
  const int wc = wid & 1;
  const int m0 = blockIdx.y * 64;
  const int n0 = blockIdx.x * 64;
  const f16* Ab = p.A;
  const f16* Wb = p.W;

  auto stage = [&](int buf, int t) {
    const int ko = t * 64;
    const int row = tid >> 3, ch = tid & 7;
    const int sk = ((ch ^ (row & 7)) << 3);
    gload16(Ab + (long long)(m0 + row) * p.lda + ko + sk, As + buf * 4096 + tid * 8);
    gload16(Wb + (long long)(n0 + row) * p.ldw + ko + sk, Bs + buf * 4096 + tid * 8);
  };

  stage(0, 0);
  stage(1, 1);

  f32x4 acc[2] = {};
  const int lr = lane & 15;
  const int lg = lane >> 4;

  for (int t = 0; t < 16; ++t) {
    if (t + 2 < 16) stage((t + 2) & 3, t + 2);
    if (t + 2 < 16)      asm volatile("s_waitcnt vmcnt(4)" ::: "memory");
    else if (t + 1 < 16) asm volatile("s_waitcnt vmcnt(2)" ::: "memory");
    else                 asm volatile("s_waitcnt vmcnt(0)" ::: "memory");
    __builtin_amdgcn_s_barrier();
    const int cur = t & 3;
#pragma unroll
    for (int ks = 0; ks < 2; ++ks) {
      f16x8 fa, fb[2];
      {
        const int r = wr * 16 + lr;
        fa = *(const f16x8*)((const char*)(As + cur * 4096) + r * 128 +
                             (((ks * 4 + lg) ^ (r & 7)) << 4));
      }
#pragma unroll
      for (int j = 0; j < 2; ++j) {
        const int r = wc * 32 + j * 16 + lr;
        fb[j] = *(const f16x8*)((const char*)(Bs + cur * 4096) + r * 128 +
                                (((ks * 4 + lg) ^ (r & 7)) << 4));
      }
#pragma unroll
      for (int j = 0; j < 2; ++j)
        acc[j] = __builtin_amdgcn_mfma_f32_16x16x32_f16(fa, fb[j], acc[j], 0, 0, 0);
    }
    asm volatile("s_waitcnt lgkmcnt(0)" ::: "memory");
  }

  const int rq = lg * 4;
#pragma unroll
  for (int j = 0; j < 2; ++j) {
    const int colb = n0 + wc * 32 + j * 16 + lr;
    const float bv = p.bias[colb];
#pragma unroll
    for (int r = 0; r < 4; ++r) {
      const int row = m0 + wr * 16 + rq + r;
      float v = acc[j][r] + bv;
      v = 1.f / (1.f + __expf(-v));
      ((f16*)p.C)[(long long)row * p.ldc + colb] = (f16)v;
    }
  }
}

// Fused flash attention, transposed-softmax form (R17: T5 setprio).
__global__ __launch_bounds__(256, 4) void fattn(const f16* __restrict__ q,
                                                const f16* __restrict__ kk,
                                                const f16* __restrict__ vt,
                                                f16* __restrict__ out) {
  __shared__ __align__(16) f16 Ks[2][64 * 64];   // [j][dk] rows 128B, swizzled
  __shared__ __align__(16) f16 Vs[2][64 * 64];   // [dk][j] rows 128B, swizzled
  __shared__ __align__(16) f16 Ps[4][16 * 64];   // Q staging, then per-wave P^T

  const int tid = threadIdx.x;
  const int lane = tid & 63;
  const int wid = tid >> 6;
  const int lr = lane & 15;
  const int lg = lane >> 4;
  const int bh = blockIdx.y;
  const int b = bh >> 4, h = bh & 15;
  const int q0 = blockIdx.x * 64;

  const f16* qp = q + (long long)bh * 65536;
  const f16* kp = kk + (long long)bh * 65536;
  const f16* vp = vt + (long long)bh * 65536;
  char* pbase = (char*)&Ps[0][0];

#pragma unroll
  for (int u = 0; u < 2; ++u) {
    const int c = u * 4 + wid;
    const int s = c * 64 + lane;
    const int row = s >> 3, ch = s & 7;
    gload16(qp + (long long)(q0 + row) * 64 + ((ch ^ (row & 7)) << 3),
            pbase + c * 1024);
  }
  asm volatile("s_waitcnt vmcnt(0)" ::: "memory");
  __syncthreads();
  f16x8 qf[2];
#pragma unroll
  for (int ks = 0; ks < 2; ++ks) {
    const int row = wid * 16 + lr;
    qf[ks] = *(const f16x8*)(pbase + row * 128 + (((ks * 4 + lg) ^ (lr & 7)) << 4));
  }
  asm volatile("s_waitcnt lgkmcnt(0)" ::: "memory");
  __syncthreads();

  f32x4 o[4] = {};
  f32x4 ol = {};
  float m_r = -1e30f;

  const f16x8 ones = {(f16)1.f, (f16)1.f, (f16)1.f, (f16)1.f,
                      (f16)1.f, (f16)1.f, (f16)1.f, (f16)1.f};

  auto stage = [&](int buf, int t) {
    const int j0 = t * 64;
#pragma unroll
    for (int u = 0; u < 2; ++u) {
      const int c = u * 4 + wid;
      const int s = c * 64 + lane;
      const int row = s >> 3, ch = s & 7;
      const int sch = (ch ^ (row & 7)) * 8;
      gload16(kp + (long long)(j0 + row) * 64 + sch, &Ks[buf][c * 512]);
      gload16(vp + (long long)row * 1024 + j0 + sch, &Vs[buf][c * 512]);
    }
  };

  stage(0, 0);

  constexpr float SCL = 0.125f * 1.44269504089f;
  for (int t = 0; t < 16; ++t) {
    asm volatile("s_waitcnt vmcnt(0)" ::: "memory");
    __builtin_amdgcn_s_barrier();
    if (t + 1 < 16) stage((t + 1) & 1, t + 1);
    const int cur = t & 1;

    f32x4 s[4] = {};
    __builtin_amdgcn_s_setprio(1);
#pragma unroll
    for (int ks = 0; ks < 2; ++ks) {
      f16x8 fk[4];
#pragma unroll
      for (int jf = 0; jf < 4; ++jf) {
        const int j = jf * 16 + lr;
        fk[jf] = *(const f16x8*)((const char*)&Ks[cur][0] + j * 128 +
                                 (((ks * 4 + lg) ^ (j & 7)) << 4));
      }
#pragma unroll
      for (int jf = 0; jf < 4; ++jf)
        s[jf] = __builtin_amdgcn_mfma_f32_16x16x32_f16(fk[jf], qf[ks], s[jf], 0, 0, 0);
    }
    __builtin_amdgcn_s_setprio(0);

    float pm = s[0][0];
#pragma unroll
    for (int jf = 0; jf < 4; ++jf)
#pragma unroll
      for (int r = 0; r < 4; ++r) pm = fmaxf(pm, s[jf][r]);
    pm = fmaxf(pm, __shfl_xor(pm, 16));
    pm = fmaxf(pm, __shfl_xor(pm, 32));
    if (__any(pm > m_r)) {
      const float mn = fmaxf(m_r, pm);
      const float sf = __builtin_exp2f((m_r - mn) * SCL);
      m_r = mn;
#pragma unroll
      for (int df = 0; df < 4; ++df)
#pragma unroll
        for (int r = 0; r < 4; ++r) o[df][r] *= sf;
#pragma unroll
      for (int r = 0; r < 4; ++r) ol[r] *= sf;
    }
    const float msc = m_r * SCL;
    float pv[4][4];
#pragma unroll
    for (int jf = 0; jf < 4; ++jf)
#pragma unroll
      for (int r = 0; r < 4; ++r)
        pv[jf][r] = __builtin_exp2f(__builtin_fmaf(s[jf][r], SCL, -msc));
    if (t == 0 && lg == 0) pv[0][0] *= 0.5f;

#pragma unroll
    for (int jf = 0; jf < 4; ++jf) {
      f16x4v pk = {(f16)pv[jf][0], (f16)pv[jf][1], (f16)pv[jf][2], (f16)pv[jf][3]};
      const int j0 = jf * 16 + lg * 4;
      *(f16x4v*)(pbase + wid * 2048 + lr * 128 +
                 (((j0 >> 3) ^ (lr & 7)) << 4) + (j0 & 7) * 2) = pk;
    }
    asm volatile("s_waitcnt lgkmcnt(0)" ::: "memory");
    __builtin_amdgcn_sched_barrier(0);

    __builtin_amdgcn_s_setprio(1);
#pragma unroll
    for (int ks = 0; ks < 2; ++ks) {
      f16x8 fp, fv[4];
      fp = *(const f16x8*)(pbase + wid * 2048 + lr * 128 +
                           (((ks * 4 + lg) ^ (lr & 7)) << 4));
#pragma unroll
      for (int df = 0; df < 4; ++df) {
        const int d = df * 16 + lr;
        fv[df] = *(const f16x8*)((const char*)&Vs[cur][0] + d * 128 +
                                 (((ks * 4 + lg) ^ (d & 7)) << 4));
      }
#pragma unroll
      for (int df = 0; df < 4; ++df)
        o[df] = __builtin_amdgcn_mfma_f32_16x16x32_f16(fv[df], fp, o[df], 0, 0, 0);
      ol = __builtin_amdgcn_mfma_f32_16x16x32_f16(ones, fp, ol, 0, 0, 0);
    }
    __builtin_amdgcn_s_setprio(0);
    if (t == 0) {
      const float hv = __shfl(pv[0][0], lane & 15);
#pragma unroll
      for (int r = 0; r < 4; ++r) ol[r] += hv;
    }
    asm volatile("s_waitcnt lgkmcnt(0)" ::: "memory");
  }

  const float inv = 1.f / ol[0];
  const long long rowi = q0 + wid * 16 + lr;
#pragma unroll
  for (int df = 0; df < 4; ++df) {
    f16x4v ov = {(f16)(o[df][0] * inv), (f16)(o[df][1] * inv),
                 (f16)(o[df][2] * inv), (f16)(o[df][3] * inv)};
    *(f16x4v*)(out + (long long)b * 1048576 + rowi * 1024 + h * 64 +
               df * 16 + lg * 4) = ov;
  }
}

// LayerNorm over D=1024, fp32 in, f16 out.
__global__ __launch_bounds__(256) void ln_k(const float* __restrict__ pre,
                                            const float* __restrict__ w,
                                            const float* __restrict__ b,
                                            f16* __restrict__ out) {
  const long long row = blockIdx.x;
  const int t = threadIdx.x;
  const float* x = pre + row * 1024;
  float4 v = *(const float4*)(x + t * 4);
  float s = v.x + v.y + v.z + v.w;
  float s2 = v.x * v.x + v.y * v.y + v.z * v.z + v.w * v.w;
#pragma unroll
  for (int o = 1; o < 64; o <<= 1) { s += __shfl_xor(s, o); s2 += __shfl_xor(s2, o); }
  __shared__ float rs[4], rs2[4];
  if ((t & 63) == 0) { rs[t >> 6] = s; rs2[t >> 6] = s2; }
  __syncthreads();
  s = rs[0] + rs[1] + rs[2] + rs[3];
  s2 = rs2[0] + rs2[1] + rs2[2] + rs2[3];
  const float mean = s * (1.f / 1024.f);
  const float var = s2 * (1.f / 1024.f) - mean * mean;
  const float inv = rsqrtf(var + 1e-5f);
  f16x4v o4;
#pragma unroll
  for (int c = 0; c < 4; ++c) {
    const float xv = (&v.x)[c];
    o4[c] = (f16)((xv - mean) * inv * w[t * 4 + c] + b[t * 4 + c]);
  }
  *(f16x4v*)(out + row * 1024 + t * 4) = o4;
}

// fp32 -> fp16, segments parallel across blockIdx.y (one dispatch).
// NT loads on the fp32 src: read-once stream must not thrash L3.
struct CvtArgs {
  const float* src[10];
  f16* dst[10];
  int n4[10];
};
__global__ __launch_bounds__(256) void cvt_par(CvtArgs a) {
  const int seg = blockIdx.y;
  const f32x4* in = (const f32x4*)a.src[seg];
  f16x4v* out = (f16x4v*)a.dst[seg];
  const int n = a.n4[seg];
  const int stride = gridDim.x * 256;
  for (int i = blockIdx.x * 256 + threadIdx.x; i < n; i += stride) {
    f32x4 v = __builtin_nontemporal_load(&in[i]);
    f16x4v o = {(f16)v[0], (f16)v[1], (f16)v[2], (f16)v[3]};
    out[i] = o;
  }
}

extern "C" void kernel_launch(void* const* d_in, const int* in_sizes, int n_in,
                              void* d_out, int out_size, void* d_ws, size_t ws_size,
                              hipStream_t stream) {
  (void)in_sizes; (void)n_in; (void)out_size; (void)ws_size;
  const float* x_in  = (const float*)d_in[0];
  const float* emb_w = (const float*)d_in[1];
  const float* emb_b = (const float*)d_in[2];
  const float* cg_w  = (const float*)d_in[3];
  const float* cg_b  = (const float*)d_in[4];
  const float* wq    = (const float*)d_in[5];
  const float* bq    = (const float*)d_in[6];
  const float* wk    = (const float*)d_in[7];
  const float* bk    = (const float*)d_in[8];
  const float* wv    = (const float*)d_in[9];
  const float* bv    = (const float*)d_in[10];
  const float* wo    = (const float*)d_in[11];
  const float* bo    = (const float*)d_in[12];
  const float* fc1w  = (const float*)d_in[13];
  const float* fc1b  = (const float*)d_in[14];
  const float* fc2w  = (const float*)d_in[15];
  const float* fc2b  = (const float*)d_in[16];
  const float* lnw   = (const float*)d_in[17];
  const float* lnb   = (const float*)d_in[18];
  const float* outw  = (const float*)d_in[19];
  const float* outb  = (const float*)d_in[20];
  float* outp = (float*)d_out;

  const size_t M1 = 1024ull * 1024ull;
  char* wsp = (char*)d_ws;
  size_t off = 0;
  auto alloc = [&](size_t bytes) -> void* {
    void* r = wsp + off;
    off += (bytes + 255) & ~(size_t)255;
    return r;
  };

  // fp16 weights
  f16* embw_h = (f16*)alloc(M1 * 2);
  f16* outw_h = (f16*)alloc(M1 * 2);
  f16* cgw_h  = (f16*)alloc(6 * M1 * 2);
  f16* wq_h   = (f16*)alloc(6 * M1 * 2);
  f16* wk_h   = (f16*)alloc(6 * M1 * 2);
  f16* wv_h   = (f16*)alloc(6 * M1 * 2);
  f16* wo_h   = (f16*)alloc(6 * M1 * 2);
  f16* fc1_h  = (f16*)alloc(6 * M1 * 2);
  f16* fc2_h  = (f16*)alloc(6 * M1 * 2);
  // fp16 activations
  f16* xh0   = (f16*)alloc(2 * M1 * 2);
  f16* xh    = (f16*)alloc(2 * M1 * 2);
  f16* xT    = (f16*)alloc(2 * M1 * 2);
  f16* cmb   = (f16*)alloc(2 * M1 * 2);
  f16* x2    = (f16*)alloc(2 * M1 * 2);
  f16* qb    = (f16*)alloc(2 * M1 * 2);
  f16* kbuf  = (f16*)alloc(2 * M1 * 2);
  f16* vT    = (f16*)alloc(2 * M1 * 2);
  f16* attnb = (f16*)alloc(2 * M1 * 2);
  f16* xf    = (f16*)alloc(2 * M1 * 2);
  f16* h1    = (f16*)alloc(2 * M1 * 2);
  // fp32 buffers
  float* resid = (float*)alloc(2 * M1 * 4);
  float* pre   = (float*)alloc(2 * M1 * 4);

  // ---- single-dispatch fp32 -> fp16 conversions (parallel segments) ----
  CvtArgs ca;
  ca.src[0] = x_in;  ca.dst[0] = xh0;    ca.n4[0] = (int)(2 * M1 / 4);
  ca.src[1] = emb_w; ca.dst[1] = embw_h; ca.n4[1] = (int)(M1 / 4);
  ca.src[2] = outw;  ca.dst[2] = outw_h; ca.n4[2] = (int)(M1 / 4);
  ca.src[3] = cg_w;  ca.dst[3] = cgw_h;  ca.n4[3] = (int)(6 * M1 / 4);
  ca.src[4] = wq;    ca.dst[4] = wq_h;   ca.n4[4] = (int)(6 * M1 / 4);
  ca.src[5] = wk;    ca.dst[5] = wk_h;   ca.n4[5] = (int)(6 * M1 / 4);
  ca.src[6] = wv;    ca.dst[6] = wv_h;   ca.n4[6] = (int)(6 * M1 / 4);
  ca.src[7] = wo;    ca.dst[7] = wo_h;   ca.n4[7] = (int)(6 * M1 / 4);
  ca.src[8] = fc1w;  ca.dst[8] = fc1_h;  ca.n4[8] = (int)(6 * M1 / 4);
  ca.src[9] = fc2w;  ca.dst[9] = fc2_h;  ca.n4[9] = (int)(6 * M1 / 4);
  cvt_par<<<dim3(512, 10), 256, 0, stream>>>(ca);

  // embedding: xh = x @ emb_w^T + emb_b
  gemm_nt<EPI_F16B><<<dim3(16, 32, 1), 512, 0, stream>>>(
      GP{xh0, embw_h, nullptr, nullptr, emb_b, nullptr, nullptr,
         xh, nullptr, nullptr, nullptr, 1024, 1024, 1024, 0, 0, 0});

  for (int i = 0; i < 6; ++i) {
    const f16* cgwi = cgw_h + (size_t)i * M1;
    const f16* wqi = wq_h + (size_t)i * M1;
    const f16* wki = wk_h + (size_t)i * M1;
    const f16* wvi = wv_h + (size_t)i * M1;
    const f16* woi = wo_h + (size_t)i * M1;
    const f16* f1i = fc1_h + (size_t)i * M1;
    const f16* f2i = fc2_h + (size_t)i * M1;

    // fused: cm = sigmoid(xh @ cg_w^T + cg_b)  AND  xT = transpose(xh)
    sig_tr<<<dim3(16, 64, 1), 512, 0, stream>>>(
        GP{xh, cgwi, xh, nullptr, cg_b + i * 1024, nullptr, nullptr,
           cmb, xT, nullptr, nullptr, 1024, 1024, 1024, 0, 0, 0});

    // x2[b] = cm[b] @ x[b]  (NT against xT)
    gemm_nt<EPI_F16><<<dim3(16, 16, 2), 512, 0, stream>>>(
        GP{cmb, xT, nullptr, nullptr, nullptr, nullptr, nullptr,
           x2, nullptr, nullptr, nullptr, 1024, 1024, 1024,
           (long long)M1, (long long)M1, (long long)M1});

    // fused q/k/v projection: q,k -> [B,H,L,DK]; v -> [B,H,DK,L]
    gemm_nt<EPI_QKV3><<<dim3(48, 32, 1), 512, 0, stream>>>(
        GP{x2, wqi, wki, wvi, bq + i * 1024, bk + i * 1024, bv + i * 1024,
           qb, kbuf, vT, nullptr, 1024, 1024, 0, 0, 0, 0});

    // fused attention
    fattn<<<dim3(16, 32), 256, 0, stream>>>(qb, kbuf, vT, attnb);

    // x = attn @ wo^T + bo  -> resid (fp32) + xf (fp16)
    gemm_nt<EPI_RESID><<<dim3(16, 32, 1), 512, 0, stream>>>(
        GP{attnb, woi, nullptr, nullptr, bo + i * 1024, nullptr, nullptr,
           resid, xf, nullptr, nullptr, 1024, 1024, 0, 0, 0, 0});
    gemm_nt<EPI_RELU><<<dim3(16, 32, 1), 512, 0, stream>>>(
        GP{xf, f1i, nullptr, nullptr, fc1b + i * 1024, nullptr, nullptr,
           h1, nullptr, nullptr, nullptr, 1024, 1024, 1024, 0, 0, 0});
    gemm_nt<EPI_FC2><<<dim3(16, 32, 1), 512, 0, stream>>>(
        GP{h1, f2i, nullptr, nullptr, fc2b + i * 1024, nullptr, nullptr,
           pre, nullptr, nullptr, resid, 1024, 1024, 0, 0, 0, 0});
    ln_k<<<dim3(2048), 256, 0, stream>>>(pre, lnw + i * 1024, lnb + i * 1024, xh);
  }

  gemm_nt<EPI_OUT><<<dim3(16, 32, 1), 512, 0, stream>>>(
      GP{xh, outw_h, nullptr, nullptr, outb, nullptr, nullptr,
         outp, nullptr, nullptr, nullptr, 1024, 1024, 0, 0, 0, 0});
}